// Round 4
// baseline (511.545 us; speedup 1.0000x reference)
//
#include <hip/hip_runtime.h>

typedef unsigned short u16;
typedef __bf16 bf16x8 __attribute__((ext_vector_type(8)));
typedef float f32x4 __attribute__((ext_vector_type(4)));
typedef u16 u16x8 __attribute__((ext_vector_type(8)));
typedef u16 u16x4 __attribute__((ext_vector_type(4)));

__device__ __forceinline__ u16 f2bf(float f) {
    union { float f; unsigned u; } v; v.f = f;
    unsigned r = v.u + 0x7FFFu + ((v.u >> 16) & 1u);
    return (u16)(r >> 16);
}

#define AS1 __attribute__((address_space(1)))
#define AS3 __attribute__((address_space(3)))
__device__ __forceinline__ void gload_lds16(const void* g, void* l) {
    __builtin_amdgcn_global_load_lds((const AS1 void*)(g), (AS3 void*)(l), 16, 0, 0);
}

// ---------------- prep: roll(-6,-6) + window partition + cast to bf16 ----------------
__global__ __launch_bounds__(256) void prep_x_kernel(const float* __restrict__ x, u16* __restrict__ xw) {
    unsigned i = ((unsigned)blockIdx.x * 256u + threadIdx.x) * 4u;
    int R = (int)(i / 768u); int c = (int)(i % 768u);
    int w = R / 144, nn = R - w * 144;
    int b = w >> 2, wi = w & 3;
    int r = nn / 12, cc = nn - r * 12;
    int sh = (wi >> 1) * 12 + r + 6; if (sh >= 24) sh -= 24;
    int sw = (wi & 1) * 12 + cc + 6; if (sw >= 24) sw -= 24;
    const float* src = x + (((size_t)b * 24 + sh) * 24 + sw) * 768 + c;
    f32x4 v = *(const f32x4*)src;
    u16x4 o; o[0] = f2bf(v[0]); o[1] = f2bf(v[1]); o[2] = f2bf(v[2]); o[3] = f2bf(v[3]);
    *(u16x4*)(xw + i) = o;
}

// ---------------- weight transpose + cast: w[K][N] -> wt[N][K] bf16 ----------------
__global__ __launch_bounds__(256) void transpose_cast_kernel(const float* __restrict__ w, u16* __restrict__ wt,
                                                             int K, int N) {
    __shared__ float tile[32][33];
    int tx = threadIdx.x & 31, ty = threadIdx.x >> 5;
    int nb = blockIdx.x * 32, kb = blockIdx.y * 32;
#pragma unroll
    for (int rr = 0; rr < 32; rr += 8) tile[rr + ty][tx] = w[(size_t)(kb + rr + ty) * N + nb + tx];
    __syncthreads();
#pragma unroll
    for (int rr = 0; rr < 32; rr += 8) wt[(size_t)(nb + rr + ty) * K + kb + tx] = f2bf(tile[tx][rr + ty]);
}

// ---------------- bias_mat[h][n][m] = rpb_table[rel_index[n*144+m]][h] ----------------
__global__ __launch_bounds__(256) void make_bias_kernel(const float* __restrict__ tab, const int* __restrict__ rel,
                                                        float* __restrict__ bm) {
    int i = blockIdx.x * 256 + threadIdx.x;
    int h = i / 20736, nm = i - h * 20736;
    bm[i] = tab[rel[nm] * 24 + h];
}

// ---------------- 256x256 BK=32, 3-buffer, 1-barrier-per-tile bf16 MFMA GEMM ----------------
// LDS: 3 buffers x 32 KB (A 16KB @ +0, B 16KB @ +16384). Tile T lives in buf T%3;
// tile T+2 staged into buf (T+2)%3 == (T-1)%3 — disjoint from read zones of tiles T and T+1,
// so stages never race reads across wave skew. One vmcnt+barrier per K-tile; vmcnt(4)
// keeps one tile's stages (4 loads/thread) in flight. BK=32 rows (64 B) make ds_read_b128
// naturally bank-balanced (8 lanes per bank-group) — no swizzle, linear staging.
#define FENCE asm volatile("" ::: "memory")
#define BARRIER __builtin_amdgcn_s_barrier()

#define STAGE_REGION(g, rowbase, ldsbase, T)                                                   \
    { _Pragma("unroll") for (int j = 0; j < 2; j++) {                                          \
        int Lb = (j * 8 + wv) * 1024;                                                          \
        int L = Lb + lane * 16;                                                                \
        const u16* src = (g) + (size_t)((rowbase) + (L >> 6)) * Kdim + (T) * 32 + ((L & 63) >> 1); \
        gload_lds16(src, (char*)(ldsbase) + Lb);                                               \
    } }

template <int EPI>
__global__ __launch_bounds__(512, 2) void gemm256_kernel(const u16* __restrict__ A, const u16* __restrict__ Bt,
                                                         const float* __restrict__ bias,
                                                         u16* __restrict__ o0, u16* __restrict__ o1, u16* __restrict__ o2,
                                                         float* __restrict__ of, int Ndim, int Kdim, int nxb, float qscale) {
    __shared__ __align__(16) u16 lds[49152];  // 96 KiB
    const int t = threadIdx.x, lane = t & 63, wv = t >> 6;
    const int wr = wv >> 2, wc = wv & 3;          // 2 x 4 wave grid
    const int l15 = lane & 15, lg = lane >> 4;
    int nwg = gridDim.x, orig = blockIdx.x;       // bijective XCD swizzle
    int q = nwg >> 3, r = nwg & 7, xcd = orig & 7, loc = orig >> 3;
    int wg = (xcd < r ? xcd * (q + 1) : r * (q + 1) + (xcd - r) * q) + loc;
    int by = wg / nxb, bx = wg - by * nxb;
    const int bm = by << 8, bn = bx << 8;

    f32x4 acc[8][4] = {};
    const int NT = Kdim >> 5;  // 24

    // prologue: tiles 0 -> buf0, 1 -> buf1
    STAGE_REGION(A, bm, (char*)lds, 0);
    STAGE_REGION(Bt, bn, (char*)lds + 16384, 0);
    STAGE_REGION(A, bm, (char*)lds + 32768, 1);
    STAGE_REGION(Bt, bn, (char*)lds + 32768 + 16384, 1);
    asm volatile("s_waitcnt vmcnt(4)" ::: "memory");
    FENCE; BARRIER;

    int ba = 0;  // buffer index of current tile
    for (int T = 0; T < NT; ++T) {
        const char* rb = (const char*)lds + ba * 32768;
        char* sb = (char*)lds + (ba >= 1 ? ba - 1 : 2) * 32768;  // (T+2)%3 == (T-1)%3
        const bool st = (T + 2 < NT);
        bf16x8 aR[8], bR[4];
        // ---- phase 1: stage A(T+2), read aR0-3 + bR0-3, MFMA quad 0 ----
        if (st) STAGE_REGION(A, bm, sb, T + 2);
#pragma unroll
        for (int mf = 0; mf < 4; mf++)
            aR[mf] = *(const bf16x8*)(rb + (wr * 128 + mf * 16 + l15) * 64 + lg * 16);
#pragma unroll
        for (int nf = 0; nf < 4; nf++)
            bR[nf] = *(const bf16x8*)(rb + 16384 + (wc * 64 + nf * 16 + l15) * 64 + lg * 16);
        __builtin_amdgcn_s_setprio(1);
#pragma unroll
        for (int mf = 0; mf < 4; mf++)
#pragma unroll
            for (int nf = 0; nf < 4; nf++)
                acc[mf][nf] = __builtin_amdgcn_mfma_f32_16x16x32_bf16(aR[mf], bR[nf], acc[mf][nf], 0, 0, 0);
        __builtin_amdgcn_s_setprio(0);
        // ---- phase 2: stage B(T+2), read aR4-7, MFMA quad 1 ----
        if (st) STAGE_REGION(Bt, bn, sb + 16384, T + 2);
#pragma unroll
        for (int mf = 4; mf < 8; mf++)
            aR[mf] = *(const bf16x8*)(rb + (wr * 128 + mf * 16 + l15) * 64 + lg * 16);
        __builtin_amdgcn_s_setprio(1);
#pragma unroll
        for (int mf = 4; mf < 8; mf++)
#pragma unroll
            for (int nf = 0; nf < 4; nf++)
                acc[mf][nf] = __builtin_amdgcn_mfma_f32_16x16x32_bf16(aR[mf], bR[nf], acc[mf][nf], 0, 0, 0);
        __builtin_amdgcn_s_setprio(0);
        // ---- tile-end sync: next tile's buffer fully landed ----
        if (T < NT - 2) { asm volatile("s_waitcnt vmcnt(4)" ::: "memory"); }
        else            { asm volatile("s_waitcnt vmcnt(0)" ::: "memory"); }
        FENCE; BARRIER;
        ba = (ba == 2) ? 0 : ba + 1;
    }

    // epilogue
#pragma unroll
    for (int mf = 0; mf < 8; mf++) {
        int Rbase = bm + wr * 128 + mf * 16 + lg * 4;
#pragma unroll
        for (int nf = 0; nf < 4; nf++) {
            int Cg = bn + wc * 64 + nf * 16 + l15;
            float bv = bias[Cg];
            if (EPI == 0) {
                int s = Cg / 768; int rem = Cg - s * 768; int h = rem >> 5; int dd = rem & 31;
#pragma unroll
                for (int rg = 0; rg < 4; rg++) {
                    int R = Rbase + rg;
                    int w2 = R / 144; int nn = R - w2 * 144;
                    float v = acc[mf][nf][rg] + bv;
                    if (s == 0)      o0[((size_t)(w2 * 24 + h) * 144 + nn) * 32 + dd] = f2bf(v * qscale);
                    else if (s == 1) o1[((size_t)(w2 * 24 + h) * 144 + nn) * 32 + dd] = f2bf(v);
                    else             o2[((size_t)(w2 * 24 + h) * 32 + dd) * 144 + nn] = f2bf(v);
                }
            } else {
#pragma unroll
                for (int rg = 0; rg < 4; rg++) {
                    int R = Rbase + rg;
                    of[(size_t)R * Ndim + Cg] = acc[mf][nf][rg] + bv;
                }
            }
        }
    }
}

// ---------------- fused window attention: 1 block per (window, head), 9 waves ----------------
__global__ __launch_bounds__(576) void attn_kernel(const u16* __restrict__ Qg, const u16* __restrict__ Kg,
                                                   const u16* __restrict__ Vg, const float* __restrict__ bias_mat,
                                                   u16* __restrict__ Ob) {
    __shared__ __align__(16) u16 Qs[144 * 40];
    __shared__ __align__(16) u16 Ks[144 * 40];
    __shared__ __align__(16) u16 Vs[32 * 160];
    __shared__ __align__(16) u16 Ps[144 * 160];
    const int bx = blockIdx.x;
    const int w = bx / 24, h = bx - w * 24;
    const int wi = w & 3, wh = wi >> 1, ww = wi & 1;
    const int t = threadIdx.x, lane = t & 63, wv = t >> 6;
    const int l15 = lane & 15, lg = lane >> 4;
    const size_t base = (size_t)bx * 4608;
    {
        int nn = t >> 2, dd = (t & 3) << 3;
        *(u16x8*)(Qs + nn * 40 + dd) = *(const u16x8*)(Qg + base + nn * 32 + dd);
        *(u16x8*)(Ks + nn * 40 + dd) = *(const u16x8*)(Kg + base + nn * 32 + dd);
        int rv = t / 18, cv = (t - rv * 18) * 8;
        int ba = (rv * 320 + cv * 2) ^ ((rv & 7) << 4);
        *(u16x8*)((char*)Vs + ba) = *(const u16x8*)(Vg + base + rv * 144 + cv);
    }
    u16x8 zz = (u16x8)0;
    if (t < 64)  { int rv = t >> 1, cv = 144 + (t & 1) * 8; int ba = (rv * 320 + cv * 2) ^ ((rv & 7) << 4); *(u16x8*)((char*)Vs + ba) = zz; }
    if (t < 288) { int rv = t >> 1, cv = 144 + (t & 1) * 8; int ba = (rv * 320 + cv * 2) ^ ((rv & 7) << 4); *(u16x8*)((char*)Ps + ba) = zz; }
    __syncthreads();

    f32x4 S[9];
    {
        bf16x8 aq = *(const bf16x8*)(Qs + (wv * 16 + l15) * 40 + lg * 8);
        f32x4 z4 = (f32x4)0.0f;
#pragma unroll
        for (int j = 0; j < 9; j++) {
            bf16x8 bk = *(const bf16x8*)(Ks + (j * 16 + l15) * 40 + lg * 8);
            S[j] = __builtin_amdgcn_mfma_f32_16x16x32_bf16(aq, bk, z4, 0, 0, 0);
        }
    }
    int regm[9];
#pragma unroll
    for (int j = 0; j < 9; j++) {
        int m = j * 16 + l15; int r = m / 12, c = m - r * 12;
        int rid = wh ? (r < 6 ? 1 : 2) : 0;
        int cid = ww ? (c < 6 ? 1 : 2) : 0;
        regm[j] = rid * 3 + cid;
    }
    const float* bh = bias_mat + h * 20736;
#pragma unroll
    for (int rg = 0; rg < 4; rg++) {
        int n = wv * 16 + lg * 4 + rg;
        int r = n / 12, c = n - r * 12;
        int rid = wh ? (r < 6 ? 1 : 2) : 0;
        int cid = ww ? (c < 6 ? 1 : 2) : 0;
        int regn = rid * 3 + cid;
        const float* bhn = bh + n * 144;
        float mx = -1e30f;
#pragma unroll
        for (int j = 0; j < 9; j++) {
            float v = S[j][rg] + bhn[j * 16 + l15];
            if (regn != regm[j]) v -= 100.0f;
            S[j][rg] = v;
            mx = fmaxf(mx, v);
        }
#pragma unroll
        for (int d = 1; d < 16; d <<= 1) mx = fmaxf(mx, __shfl_xor(mx, d));
        float sum = 0.0f;
#pragma unroll
        for (int j = 0; j < 9; j++) { float e = __expf(S[j][rg] - mx); S[j][rg] = e; sum += e; }
#pragma unroll
        for (int d = 1; d < 16; d <<= 1) sum += __shfl_xor(sum, d);
        float inv = 1.0f / sum;
#pragma unroll
        for (int j = 0; j < 9; j++) {
            int ba = (n * 320 + (j * 16 + l15) * 2) ^ ((n & 7) << 4);
            *(u16*)((char*)Ps + ba) = f2bf(S[j][rg] * inv);
        }
    }
    __syncthreads();
    f32x4 o0 = (f32x4)0.0f, o1 = (f32x4)0.0f;
#pragma unroll
    for (int ks = 0; ks < 5; ks++) {
        int k2 = (ks * 32 + lg * 8) * 2;
        int ra = wv * 16 + l15;
        bf16x8 ap = *(const bf16x8*)((char*)Ps + ((ra * 320 + k2) ^ ((ra & 7) << 4)));
        int rv0 = l15, rv1 = 16 + l15;
        bf16x8 b0 = *(const bf16x8*)((char*)Vs + ((rv0 * 320 + k2) ^ ((rv0 & 7) << 4)));
        bf16x8 b1 = *(const bf16x8*)((char*)Vs + ((rv1 * 320 + k2) ^ ((rv1 & 7) << 4)));
        o0 = __builtin_amdgcn_mfma_f32_16x16x32_bf16(ap, b0, o0, 0, 0, 0);
        o1 = __builtin_amdgcn_mfma_f32_16x16x32_bf16(ap, b1, o1, 0, 0, 0);
    }
    size_t ob = (size_t)w * 110592 + (size_t)h * 32;
#pragma unroll
    for (int rg = 0; rg < 4; rg++) {
        int n = wv * 16 + lg * 4 + rg;
        Ob[ob + (size_t)n * 768 + l15]      = f2bf(o0[rg]);
        Ob[ob + (size_t)n * 768 + 16 + l15] = f2bf(o1[rg]);
    }
}

// ---------------- L2 norm + window-merge + reverse shift ----------------
__global__ __launch_bounds__(256) void norm_kernel(const float* __restrict__ raw, float* __restrict__ out) {
    int R = blockIdx.x * 4 + (threadIdx.x >> 6);
    int lane = threadIdx.x & 63;
    const float* src = raw + (size_t)R * 768;
    f32x4 v0 = *(const f32x4*)(src + lane * 4);
    f32x4 v1 = *(const f32x4*)(src + lane * 4 + 256);
    f32x4 v2 = *(const f32x4*)(src + lane * 4 + 512);
    float ss = v0[0]*v0[0] + v0[1]*v0[1] + v0[2]*v0[2] + v0[3]*v0[3]
             + v1[0]*v1[0] + v1[1]*v1[1] + v1[2]*v1[2] + v1[3]*v1[3]
             + v2[0]*v2[0] + v2[1]*v2[1] + v2[2]*v2[2] + v2[3]*v2[3];
#pragma unroll
    for (int d = 1; d < 64; d <<= 1) ss += __shfl_xor(ss, d);
    float inv = 1.0f / sqrtf(ss + 1e-6f);
    int w = R / 144, nn = R - w * 144;
    int b = w >> 2, wi = w & 3;
    int r = nn / 12, cc = nn - r * 12;
    int oh = (wi >> 1) * 12 + r + 6; if (oh >= 24) oh -= 24;
    int ow = (wi & 1) * 12 + cc + 6; if (ow >= 24) ow -= 24;
    float* dst = out + (((size_t)b * 24 + oh) * 24 + ow) * 768;
    v0 *= inv; v1 *= inv; v2 *= inv;
    *(f32x4*)(dst + lane * 4) = v0;
    *(f32x4*)(dst + lane * 4 + 256) = v1;
    *(f32x4*)(dst + lane * 4 + 512) = v2;
}

extern "C" void kernel_launch(void* const* d_in, const int* in_sizes, int n_in,
                              void* d_out, int out_size, void* d_ws, size_t ws_size,
                              hipStream_t stream) {
    const float* x      = (const float*)d_in[0];
    const float* qkv_w  = (const float*)d_in[1];
    const float* qkv_b  = (const float*)d_in[2];
    const float* proj_w = (const float*)d_in[3];
    const float* proj_b = (const float*)d_in[4];
    const float* rpb    = (const float*)d_in[5];
    const int*   rel    = (const int*)d_in[6];

    char* ws = (char*)d_ws;
    const size_t SZ = 56623104;  // 36864*768*2 bytes
    u16*   xw   = (u16*)(ws);
    u16*   Qb   = (u16*)(ws + SZ);
    u16*   Kb   = (u16*)(ws + 2 * SZ);
    u16*   Vt   = (u16*)(ws + 3 * SZ);
    u16*   Ob   = (u16*)(ws + 4 * SZ);
    u16*   qwt  = (u16*)(ws + 5 * SZ);
    u16*   pwt  = (u16*)(ws + 5 * SZ + 3538944);
    float* bm   = (float*)(ws + 5 * SZ + 3538944 + 1179648);
    float* raw  = (float*)(ws);  // aliases xw+Qb (dead by GEMM2)

    prep_x_kernel<<<27648, 256, 0, stream>>>(x, xw);
    transpose_cast_kernel<<<dim3(72, 24), 256, 0, stream>>>(qkv_w, qwt, 768, 2304);
    transpose_cast_kernel<<<dim3(24, 24), 256, 0, stream>>>(proj_w, pwt, 768, 768);
    make_bias_kernel<<<1944, 256, 0, stream>>>(rpb, rel, bm);

    gemm256_kernel<0><<<1296, 512, 0, stream>>>(xw, qwt, qkv_b, Qb, Kb, Vt, nullptr,
                                                2304, 768, 9, 0.17677669529663687f);
    attn_kernel<<<6144, 576, 0, stream>>>(Qb, Kb, Vt, bm, Ob);
    gemm256_kernel<1><<<432, 512, 0, stream>>>(Ob, pwt, proj_b, nullptr, nullptr, nullptr,
                                               raw, 768, 768, 3, 1.0f);
    norm_kernel<<<9216, 256, 0, stream>>>(raw, (float*)d_out);
}

// Round 6
// 505.090 us; speedup vs baseline: 1.0128x; 1.0128x over previous
//
#include <hip/hip_runtime.h>

typedef unsigned short u16;
typedef __bf16 bf16x8 __attribute__((ext_vector_type(8)));
typedef float f32x4 __attribute__((ext_vector_type(4)));
typedef u16 u16x8 __attribute__((ext_vector_type(8)));
typedef u16 u16x4 __attribute__((ext_vector_type(4)));

__device__ __forceinline__ u16 f2bf(float f) {
    union { float f; unsigned u; } v; v.f = f;
    unsigned r = v.u + 0x7FFFu + ((v.u >> 16) & 1u);
    return (u16)(r >> 16);
}

#define AS1 __attribute__((address_space(1)))
#define AS3 __attribute__((address_space(3)))
__device__ __forceinline__ void gload_lds16(const void* g, void* l) {
    __builtin_amdgcn_global_load_lds((const AS1 void*)(g), (AS3 void*)(l), 16, 0, 0);
}

// Panel layout for all GEMM operands: [panel = idx>>8][ktile = k>>5][row = idx&255][kk = k&31]
// -> every 256x32 tile is a contiguous 16 KB block; GEMM staging is pure contiguous bursts.

// ---------------- prep: roll(-6,-6) + window partition + cast + PANELIZE ----------------
__global__ __launch_bounds__(256) void prep_x_kernel(const float* __restrict__ x, u16* __restrict__ xw) {
    unsigned i = ((unsigned)blockIdx.x * 256u + threadIdx.x) * 4u;
    int R = (int)(i / 768u); int c = (int)(i % 768u);
    int w = R / 144, nn = R - w * 144;
    int b = w >> 2, wi = w & 3;
    int r = nn / 12, cc = nn - r * 12;
    int sh = (wi >> 1) * 12 + r + 6; if (sh >= 24) sh -= 24;
    int sw = (wi & 1) * 12 + cc + 6; if (sw >= 24) sw -= 24;
    const float* src = x + (((size_t)b * 24 + sh) * 24 + sw) * 768 + c;
    f32x4 v = *(const f32x4*)src;
    u16x4 o; o[0] = f2bf(v[0]); o[1] = f2bf(v[1]); o[2] = f2bf(v[2]); o[3] = f2bf(v[3]);
    size_t idx = ((size_t)(R >> 8) * 24 + (c >> 5)) * 8192 + (R & 255) * 32 + (c & 31);
    *(u16x4*)(xw + idx) = o;
}

// ---------------- weight transpose + cast + panelize: w[K][N] -> wt[panel(n)][kt][n&255][k&31] ----------------
__global__ __launch_bounds__(256) void transpose_cast_kernel(const float* __restrict__ w, u16* __restrict__ wt,
                                                             int K, int N) {
    __shared__ float tile[32][33];
    int tx = threadIdx.x & 31, ty = threadIdx.x >> 5;
    int nb = blockIdx.x * 32, kb = blockIdx.y * 32;
#pragma unroll
    for (int rr = 0; rr < 32; rr += 8) tile[rr + ty][tx] = w[(size_t)(kb + rr + ty) * N + nb + tx];
    __syncthreads();
#pragma unroll
    for (int rr = 0; rr < 32; rr += 8) {
        int n = nb + rr + ty, k = kb + tx;
        wt[((size_t)(n >> 8) * 24 + (k >> 5)) * 8192 + (n & 255) * 32 + (k & 31)] = f2bf(tile[tx][rr + ty]);
    }
}

// ---------------- bias_mat[h][n][m] = rpb_table[rel_index[n*144+m]][h] ----------------
__global__ __launch_bounds__(256) void make_bias_kernel(const float* __restrict__ tab, const int* __restrict__ rel,
                                                        float* __restrict__ bm) {
    int i = blockIdx.x * 256 + threadIdx.x;
    int h = i / 20736, nm = i - h * 20736;
    bm[i] = tab[rel[nm] * 24 + h];
}

// ---------------- 256x256 BK=32, 4-buffer depth-3, 1-barrier-per-tile, contiguous staging ----------------
// LDS: 4 buffers x 32 KB (byte stride 32768): A 16 KB @ +0, B 16 KB @ +16384.
#define FENCE asm volatile("" ::: "memory")
#define BARRIER __builtin_amdgcn_s_barrier()

// tile (panel p, ktile T) = contiguous 16 KB at gp; 512 threads x 2 insts x 16 B, linear LDS.
#define STAGE_TILE(gp, ldsoff)                                                                 \
    { const char* srcb = (const char*)(gp);                                                    \
      _Pragma("unroll") for (int j = 0; j < 2; j++) {                                          \
        int off = j * 8192 + t * 16;                                                           \
        gload_lds16(srcb + off, (char*)lds + (ldsoff) + off);                                  \
    } }

template <int EPI>
__global__ __launch_bounds__(512, 2) void gemm256_kernel(const u16* __restrict__ A, const u16* __restrict__ Bt,
                                                         const float* __restrict__ bias,
                                                         u16* __restrict__ o0, u16* __restrict__ o1, u16* __restrict__ o2,
                                                         float* __restrict__ of, int Ndim, int Kdim, int nxb, float qscale) {
    __shared__ __align__(16) u16 lds[65536];  // 128 KiB = 4 buffers x 32 KB
    const int t = threadIdx.x, lane = t & 63, wv = t >> 6;
    const int wr = wv >> 2, wc = wv & 3;          // 2 x 4 wave grid
    const int l15 = lane & 15, lg = lane >> 4;
    int nwg = gridDim.x, orig = blockIdx.x;       // bijective XCD swizzle
    int q = nwg >> 3, r = nwg & 7, xcd = orig & 7, loc = orig >> 3;
    int wg = (xcd < r ? xcd * (q + 1) : r * (q + 1) + (xcd - r) * q) + loc;
    int by = wg / nxb, bx = wg - by * nxb;
    const int bm = by << 8, bn = bx << 8;

    f32x4 acc[8][4] = {};
    const int NT = Kdim >> 5;  // 24
    const u16* Ap = A + (size_t)(bm >> 8) * NT * 8192;   // A panel base
    const u16* Bp = Bt + (size_t)(bn >> 8) * NT * 8192;  // B panel base

    // prologue: tiles 0,1,2 -> bufs 0,1,2 (buffer byte stride 32768; B at +16384)
#pragma unroll
    for (int T0 = 0; T0 < 3; T0++) {
        STAGE_TILE(Ap + T0 * 8192, T0 * 32768);
        STAGE_TILE(Bp + T0 * 8192, T0 * 32768 + 16384);
    }
    asm volatile("s_waitcnt vmcnt(8)" ::: "memory");
    FENCE; BARRIER;

    for (int T = 0; T < NT; ++T) {
        const char* rb = (const char*)lds + (T & 3) * 32768;
        const int sbo = ((T + 3) & 3) * 32768;
        if (T + 3 < NT) {
            STAGE_TILE(Ap + (T + 3) * 8192, sbo);
            STAGE_TILE(Bp + (T + 3) * 8192, sbo + 16384);
        }
        bf16x8 aR[8], bR[4];
#pragma unroll
        for (int mf = 0; mf < 4; mf++)
            aR[mf] = *(const bf16x8*)(rb + (wr * 128 + mf * 16 + l15) * 64 + lg * 16);
#pragma unroll
        for (int nf = 0; nf < 4; nf++)
            bR[nf] = *(const bf16x8*)(rb + 16384 + (wc * 64 + nf * 16 + l15) * 64 + lg * 16);
        __builtin_amdgcn_s_setprio(1);
#pragma unroll
        for (int mf = 0; mf < 4; mf++)
#pragma unroll
            for (int nf = 0; nf < 4; nf++)
                acc[mf][nf] = __builtin_amdgcn_mfma_f32_16x16x32_bf16(aR[mf], bR[nf], acc[mf][nf], 0, 0, 0);
        __builtin_amdgcn_s_setprio(0);
#pragma unroll
        for (int mf = 4; mf < 8; mf++)
            aR[mf] = *(const bf16x8*)(rb + (wr * 128 + mf * 16 + l15) * 64 + lg * 16);
        __builtin_amdgcn_s_setprio(1);
#pragma unroll
        for (int mf = 4; mf < 8; mf++)
#pragma unroll
            for (int nf = 0; nf < 4; nf++)
                acc[mf][nf] = __builtin_amdgcn_mfma_f32_16x16x32_bf16(aR[mf], bR[nf], acc[mf][nf], 0, 0, 0);
        __builtin_amdgcn_s_setprio(0);
        // tile-end sync: ensure tile T+1's stages landed (counted, never over-drained)
        if (T + 3 < NT)      { asm volatile("s_waitcnt vmcnt(8)" ::: "memory"); }
        else if (T + 2 < NT) { asm volatile("s_waitcnt vmcnt(4)" ::: "memory"); }
        else                 { asm volatile("s_waitcnt vmcnt(0)" ::: "memory"); }
        FENCE; BARRIER;
    }

    // epilogue
#pragma unroll
    for (int mf = 0; mf < 8; mf++) {
        int Rbase = bm + wr * 128 + mf * 16 + lg * 4;
#pragma unroll
        for (int nf = 0; nf < 4; nf++) {
            int Cg = bn + wc * 64 + nf * 16 + l15;
            float bv = bias[Cg];
            if (EPI == 0) {
                int s = Cg / 768; int rem = Cg - s * 768; int h = rem >> 5; int dd = rem & 31;
#pragma unroll
                for (int rg = 0; rg < 4; rg++) {
                    int R = Rbase + rg;
                    int w2 = R / 144; int nn = R - w2 * 144;
                    float v = acc[mf][nf][rg] + bv;
                    if (s == 0)      o0[((size_t)(w2 * 24 + h) * 144 + nn) * 32 + dd] = f2bf(v * qscale);
                    else if (s == 1) o1[((size_t)(w2 * 24 + h) * 144 + nn) * 32 + dd] = f2bf(v);
                    else             o2[((size_t)(w2 * 24 + h) * 32 + dd) * 144 + nn] = f2bf(v);
                }
            } else {
#pragma unroll
                for (int rg = 0; rg < 4; rg++) {
                    int R = Rbase + rg;
                    of[(size_t)R * Ndim + Cg] = acc[mf][nf][rg] + bv;
                }
            }
        }
    }
}

// ---------------- fused window attention: 1 block per (window, head), 9 waves ----------------
__global__ __launch_bounds__(576) void attn_kernel(const u16* __restrict__ Qg, const u16* __restrict__ Kg,
                                                   const u16* __restrict__ Vg, const float* __restrict__ bias_mat,
                                                   u16* __restrict__ Ob) {
    __shared__ __align__(16) u16 Qs[144 * 40];
    __shared__ __align__(16) u16 Ks[144 * 40];
    __shared__ __align__(16) u16 Vs[32 * 160];
    __shared__ __align__(16) u16 Ps[144 * 160];
    const int bx = blockIdx.x;
    const int w = bx / 24, h = bx - w * 24;
    const int wi = w & 3, wh = wi >> 1, ww = wi & 1;
    const int t = threadIdx.x, lane = t & 63, wv = t >> 6;
    const int l15 = lane & 15, lg = lane >> 4;
    const size_t base = (size_t)bx * 4608;
    {
        int nn = t >> 2, dd = (t & 3) << 3;
        *(u16x8*)(Qs + nn * 40 + dd) = *(const u16x8*)(Qg + base + nn * 32 + dd);
        *(u16x8*)(Ks + nn * 40 + dd) = *(const u16x8*)(Kg + base + nn * 32 + dd);
        int rv = t / 18, cv = (t - rv * 18) * 8;
        int ba = (rv * 320 + cv * 2) ^ ((rv & 7) << 4);
        *(u16x8*)((char*)Vs + ba) = *(const u16x8*)(Vg + base + rv * 144 + cv);
    }
    u16x8 zz = (u16x8)0;
    if (t < 64)  { int rv = t >> 1, cv = 144 + (t & 1) * 8; int ba = (rv * 320 + cv * 2) ^ ((rv & 7) << 4); *(u16x8*)((char*)Vs + ba) = zz; }
    if (t < 288) { int rv = t >> 1, cv = 144 + (t & 1) * 8; int ba = (rv * 320 + cv * 2) ^ ((rv & 7) << 4); *(u16x8*)((char*)Ps + ba) = zz; }
    __syncthreads();

    f32x4 S[9];
    {
        bf16x8 aq = *(const bf16x8*)(Qs + (wv * 16 + l15) * 40 + lg * 8);
        f32x4 z4 = (f32x4)0.0f;
#pragma unroll
        for (int j = 0; j < 9; j++) {
            bf16x8 bk = *(const bf16x8*)(Ks + (j * 16 + l15) * 40 + lg * 8);
            S[j] = __builtin_amdgcn_mfma_f32_16x16x32_bf16(aq, bk, z4, 0, 0, 0);
        }
    }
    int regm[9];
#pragma unroll
    for (int j = 0; j < 9; j++) {
        int m = j * 16 + l15; int r = m / 12, c = m - r * 12;
        int rid = wh ? (r < 6 ? 1 : 2) : 0;
        int cid = ww ? (c < 6 ? 1 : 2) : 0;
        regm[j] = rid * 3 + cid;
    }
    const float* bh = bias_mat + h * 20736;
#pragma unroll
    for (int rg = 0; rg < 4; rg++) {
        int n = wv * 16 + lg * 4 + rg;
        int r = n / 12, c = n - r * 12;
        int rid = wh ? (r < 6 ? 1 : 2) : 0;
        int cid = ww ? (c < 6 ? 1 : 2) : 0;
        int regn = rid * 3 + cid;
        const float* bhn = bh + n * 144;
        float mx = -1e30f;
#pragma unroll
        for (int j = 0; j < 9; j++) {
            float v = S[j][rg] + bhn[j * 16 + l15];
            if (regn != regm[j]) v -= 100.0f;
            S[j][rg] = v;
            mx = fmaxf(mx, v);
        }
#pragma unroll
        for (int d = 1; d < 16; d <<= 1) mx = fmaxf(mx, __shfl_xor(mx, d));
        float sum = 0.0f;
#pragma unroll
        for (int j = 0; j < 9; j++) { float e = __expf(S[j][rg] - mx); S[j][rg] = e; sum += e; }
#pragma unroll
        for (int d = 1; d < 16; d <<= 1) sum += __shfl_xor(sum, d);
        float inv = 1.0f / sum;
#pragma unroll
        for (int j = 0; j < 9; j++) {
            int ba = (n * 320 + (j * 16 + l15) * 2) ^ ((n & 7) << 4);
            *(u16*)((char*)Ps + ba) = f2bf(S[j][rg] * inv);
        }
    }
    __syncthreads();
    f32x4 o0 = (f32x4)0.0f, o1 = (f32x4)0.0f;
#pragma unroll
    for (int ks = 0; ks < 5; ks++) {
        int k2 = (ks * 32 + lg * 8) * 2;
        int ra = wv * 16 + l15;
        bf16x8 ap = *(const bf16x8*)((char*)Ps + ((ra * 320 + k2) ^ ((ra & 7) << 4)));
        int rv0 = l15, rv1 = 16 + l15;
        bf16x8 b0 = *(const bf16x8*)((char*)Vs + ((rv0 * 320 + k2) ^ ((rv0 & 7) << 4)));
        bf16x8 b1 = *(const bf16x8*)((char*)Vs + ((rv1 * 320 + k2) ^ ((rv1 & 7) << 4)));
        o0 = __builtin_amdgcn_mfma_f32_16x16x32_bf16(ap, b0, o0, 0, 0, 0);
        o1 = __builtin_amdgcn_mfma_f32_16x16x32_bf16(ap, b1, o1, 0, 0, 0);
    }
    // write Ob in PANEL layout for the proj GEMM: R = w*144+n rows, ch = h*32+d cols
#pragma unroll
    for (int rg = 0; rg < 4; rg++) {
        int n = wv * 16 + lg * 4 + rg;
        int R = w * 144 + n;
        size_t idx = ((size_t)(R >> 8) * 24 + h) * 8192 + (R & 255) * 32;
        Ob[idx + l15]      = f2bf(o0[rg]);
        Ob[idx + 16 + l15] = f2bf(o1[rg]);
    }
}

// ---------------- L2 norm + window-merge + reverse shift ----------------
__global__ __launch_bounds__(256) void norm_kernel(const float* __restrict__ raw, float* __restrict__ out) {
    int R = blockIdx.x * 4 + (threadIdx.x >> 6);
    int lane = threadIdx.x & 63;
    const float* src = raw + (size_t)R * 768;
    f32x4 v0 = *(const f32x4*)(src + lane * 4);
    f32x4 v1 = *(const f32x4*)(src + lane * 4 + 256);
    f32x4 v2 = *(const f32x4*)(src + lane * 4 + 512);
    float ss = v0[0]*v0[0] + v0[1]*v0[1] + v0[2]*v0[2] + v0[3]*v0[3]
             + v1[0]*v1[0] + v1[1]*v1[1] + v1[2]*v1[2] + v1[3]*v1[3]
             + v2[0]*v2[0] + v2[1]*v2[1] + v2[2]*v2[2] + v2[3]*v2[3];
#pragma unroll
    for (int d = 1; d < 64; d <<= 1) ss += __shfl_xor(ss, d);
    float inv = 1.0f / sqrtf(ss + 1e-6f);
    int w = R / 144, nn = R - w * 144;
    int b = w >> 2, wi = w & 3;
    int r = nn / 12, cc = nn - r * 12;
    int oh = (wi >> 1) * 12 + r + 6; if (oh >= 24) oh -= 24;
    int ow = (wi & 1) * 12 + cc + 6; if (ow >= 24) ow -= 24;
    float* dst = out + (((size_t)b * 24 + oh) * 24 + ow) * 768;
    v0 *= inv; v1 *= inv; v2 *= inv;
    *(f32x4*)(dst + lane * 4) = v0;
    *(f32x4*)(dst + lane * 4 + 256) = v1;
    *(f32x4*)(dst + lane * 4 + 512) = v2;
}

extern "C" void kernel_launch(void* const* d_in, const int* in_sizes, int n_in,
                              void* d_out, int out_size, void* d_ws, size_t ws_size,
                              hipStream_t stream) {
    const float* x      = (const float*)d_in[0];
    const float* qkv_w  = (const float*)d_in[1];
    const float* qkv_b  = (const float*)d_in[2];
    const float* proj_w = (const float*)d_in[3];
    const float* proj_b = (const float*)d_in[4];
    const float* rpb    = (const float*)d_in[5];
    const int*   rel    = (const int*)d_in[6];

    char* ws = (char*)d_ws;
    const size_t SZ = 56623104;  // 36864*768*2 bytes
    u16*   xw   = (u16*)(ws);
    u16*   Qb   = (u16*)(ws + SZ);
    u16*   Kb   = (u16*)(ws + 2 * SZ);
    u16*   Vt   = (u16*)(ws + 3 * SZ);
    u16*   Ob   = (u16*)(ws + 4 * SZ);
    u16*   qwt  = (u16*)(ws + 5 * SZ);
    u16*   pwt  = (u16*)(ws + 5 * SZ + 3538944);
    float* bm   = (float*)(ws + 5 * SZ + 3538944 + 1179648);
    float* raw  = (float*)(ws);  // aliases xw+Qb (dead by GEMM2)

    prep_x_kernel<<<27648, 256, 0, stream>>>(x, xw);
    transpose_cast_kernel<<<dim3(72, 24), 256, 0, stream>>>(qkv_w, qwt, 768, 2304);
    transpose_cast_kernel<<<dim3(24, 24), 256, 0, stream>>>(proj_w, pwt, 768, 768);
    make_bias_kernel<<<1944, 256, 0, stream>>>(rpb, rel, bm);

    gemm256_kernel<0><<<1296, 512, 0, stream>>>(xw, qwt, qkv_b, Qb, Kb, Vt, nullptr,
                                                2304, 768, 9, 0.17677669529663687f);
    attn_kernel<<<6144, 576, 0, stream>>>(Qb, Kb, Vt, bm, Ob);
    gemm256_kernel<1><<<432, 512, 0, stream>>>(Ob, pwt, proj_b, nullptr, nullptr, nullptr,
                                               raw, 768, 768, 3, 1.0f);
    norm_kernel<<<9216, 256, 0, stream>>>(raw, (float*)d_out);
}

// Round 7
// 473.524 us; speedup vs baseline: 1.0803x; 1.0667x over previous
//
#include <hip/hip_runtime.h>

typedef unsigned short u16;
typedef __bf16 bf16x8 __attribute__((ext_vector_type(8)));
typedef float f32x4 __attribute__((ext_vector_type(4)));
typedef u16 u16x8 __attribute__((ext_vector_type(8)));
typedef u16 u16x4 __attribute__((ext_vector_type(4)));

__device__ __forceinline__ u16 f2bf(float f) {
    union { float f; unsigned u; } v; v.f = f;
    unsigned r = v.u + 0x7FFFu + ((v.u >> 16) & 1u);
    return (u16)(r >> 16);
}

#define AS1 __attribute__((address_space(1)))
#define AS3 __attribute__((address_space(3)))
__device__ __forceinline__ void gload_lds16(const void* g, void* l) {
    __builtin_amdgcn_global_load_lds((const AS1 void*)(g), (AS3 void*)(l), 16, 0, 0);
}

// Panel layout (128-row blocks): [panel = R>>7][ktile = k>>5][row = R&127][kk = k&31]
// -> every 128x32 tile is a contiguous 8 KB block; staging is pure contiguous 1KB bursts.

// ---------------- prep: roll(-6,-6) + window partition + cast + PANELIZE ----------------
__global__ __launch_bounds__(256) void prep_x_kernel(const float* __restrict__ x, u16* __restrict__ xw) {
    unsigned i = ((unsigned)blockIdx.x * 256u + threadIdx.x) * 4u;
    int R = (int)(i / 768u); int c = (int)(i % 768u);
    int w = R / 144, nn = R - w * 144;
    int b = w >> 2, wi = w & 3;
    int r = nn / 12, cc = nn - r * 12;
    int sh = (wi >> 1) * 12 + r + 6; if (sh >= 24) sh -= 24;
    int sw = (wi & 1) * 12 + cc + 6; if (sw >= 24) sw -= 24;
    const float* src = x + (((size_t)b * 24 + sh) * 24 + sw) * 768 + c;
    f32x4 v = *(const f32x4*)src;
    u16x4 o; o[0] = f2bf(v[0]); o[1] = f2bf(v[1]); o[2] = f2bf(v[2]); o[3] = f2bf(v[3]);
    size_t idx = ((size_t)(R >> 7) * 24 + (c >> 5)) * 4096 + (R & 127) * 32 + (c & 31);
    *(u16x4*)(xw + idx) = o;
}

// ---------------- weight transpose + cast + panelize: w[K][N] -> wt[panel(n)][kt][n&127][k&31] ----------------
__global__ __launch_bounds__(256) void transpose_cast_kernel(const float* __restrict__ w, u16* __restrict__ wt,
                                                             int K, int N) {
    __shared__ float tile[32][33];
    int tx = threadIdx.x & 31, ty = threadIdx.x >> 5;
    int nb = blockIdx.x * 32, kb = blockIdx.y * 32;
#pragma unroll
    for (int rr = 0; rr < 32; rr += 8) tile[rr + ty][tx] = w[(size_t)(kb + rr + ty) * N + nb + tx];
    __syncthreads();
#pragma unroll
    for (int rr = 0; rr < 32; rr += 8) {
        int n = nb + rr + ty, k = kb + tx;
        wt[((size_t)(n >> 7) * 24 + (k >> 5)) * 4096 + (n & 127) * 32 + (k & 31)] = f2bf(tile[tx][rr + ty]);
    }
}

// ---------------- bias_mat[h][n][m] = rpb_table[rel_index[n*144+m]][h] ----------------
__global__ __launch_bounds__(256) void make_bias_kernel(const float* __restrict__ tab, const int* __restrict__ rel,
                                                        float* __restrict__ bm) {
    int i = blockIdx.x * 256 + threadIdx.x;
    int h = i / 20736, nm = i - h * 20736;
    bm[i] = tab[rel[nm] * 24 + h];
}

// ---------------- 128x128 BK=32, 4 waves, 3 buffers x 16KB, 3 blocks/CU, counted vmcnt ----------------
#define FENCE asm volatile("" ::: "memory")
#define BARRIER __builtin_amdgcn_s_barrier()

// tile = contiguous 8 KB at gp; 256 threads x 2 insts x 16 B, linear LDS.
#define STAGE_TILE(gp, ldsoff)                                                                 \
    { const char* srcb = (const char*)(gp);                                                    \
      _Pragma("unroll") for (int j = 0; j < 2; j++) {                                          \
        int off = j * 4096 + t * 16;                                                           \
        gload_lds16(srcb + off, (char*)lds + (ldsoff) + off);                                  \
    } }

template <int EPI>
__global__ __launch_bounds__(256, 3) void gemm128_kernel(const u16* __restrict__ A, const u16* __restrict__ Bt,
                                                         const float* __restrict__ bias,
                                                         u16* __restrict__ o0, u16* __restrict__ o1, u16* __restrict__ o2,
                                                         float* __restrict__ of, int Ndim, int Kdim, int nxb, float qscale) {
    __shared__ __align__(16) u16 lds[24576];  // 48 KiB = 3 buffers x 16 KB (A 8K @ +0, B 8K @ +8192)
    const int t = threadIdx.x, lane = t & 63, wv = t >> 6;
    const int wr = wv >> 1, wc = wv & 1;          // 2 x 2 wave grid, 64x64 out per wave
    const int l15 = lane & 15, lg = lane >> 4;
    int nwg = gridDim.x, orig = blockIdx.x;       // bijective XCD swizzle
    int q = nwg >> 3, r = nwg & 7, xcd = orig & 7, loc = orig >> 3;
    int wg = (xcd < r ? xcd * (q + 1) : r * (q + 1) + (xcd - r) * q) + loc;
    int by = wg / nxb, bx = wg - by * nxb;
    const int bm = by << 7, bn = bx << 7;

    f32x4 acc[4][4] = {};
    const int NT = Kdim >> 5;  // 24
    const u16* Ap = A + (size_t)(bm >> 7) * NT * 4096;   // A panel base
    const u16* Bp = Bt + (size_t)(bn >> 7) * NT * 4096;  // B panel base

    // prologue: tiles 0,1 -> bufs 0,1
    STAGE_TILE(Ap, 0);
    STAGE_TILE(Bp, 8192);
    STAGE_TILE(Ap + 4096, 16384);
    STAGE_TILE(Bp + 4096, 16384 + 8192);
    asm volatile("s_waitcnt vmcnt(4)" ::: "memory");
    FENCE; BARRIER;

    int ba = 0;  // buffer of current tile (T%3)
    for (int T = 0; T < NT; ++T) {
        const char* rb = (const char*)lds + ba * 16384;
        char* sb = (char*)lds + (ba >= 1 ? ba - 1 : 2) * 16384;  // (T+2)%3
        if (T + 2 < NT) {
            STAGE_TILE(Ap + (T + 2) * 4096, sb - (char*)lds);
            STAGE_TILE(Bp + (T + 2) * 4096, sb - (char*)lds + 8192);
        }
        bf16x8 aR[4], bR[4];
#pragma unroll
        for (int mf = 0; mf < 4; mf++)
            aR[mf] = *(const bf16x8*)(rb + (wr * 64 + mf * 16 + l15) * 64 + lg * 16);
#pragma unroll
        for (int nf = 0; nf < 4; nf++)
            bR[nf] = *(const bf16x8*)(rb + 8192 + (wc * 64 + nf * 16 + l15) * 64 + lg * 16);
        __builtin_amdgcn_s_setprio(1);
#pragma unroll
        for (int mf = 0; mf < 4; mf++)
#pragma unroll
            for (int nf = 0; nf < 4; nf++)
                acc[mf][nf] = __builtin_amdgcn_mfma_f32_16x16x32_bf16(aR[mf], bR[nf], acc[mf][nf], 0, 0, 0);
        __builtin_amdgcn_s_setprio(0);
        if (T + 2 < NT)      { asm volatile("s_waitcnt vmcnt(4)" ::: "memory"); FENCE; BARRIER; }
        else if (T + 1 < NT) { asm volatile("s_waitcnt vmcnt(0)" ::: "memory"); FENCE; BARRIER; }
        ba = (ba == 2) ? 0 : ba + 1;
    }

    // epilogue
#pragma unroll
    for (int mf = 0; mf < 4; mf++) {
        int Rbase = bm + wr * 64 + mf * 16 + lg * 4;
#pragma unroll
        for (int nf = 0; nf < 4; nf++) {
            int Cg = bn + wc * 64 + nf * 16 + l15;
            float bv = bias[Cg];
            if (EPI == 0) {
                int s = Cg / 768; int rem = Cg - s * 768; int h = rem >> 5; int dd = rem & 31;
#pragma unroll
                for (int rg = 0; rg < 4; rg++) {
                    int R = Rbase + rg;
                    int w2 = R / 144; int nn = R - w2 * 144;
                    float v = acc[mf][nf][rg] + bv;
                    if (s == 0)      o0[((size_t)(w2 * 24 + h) * 144 + nn) * 32 + dd] = f2bf(v * qscale);
                    else if (s == 1) o1[((size_t)(w2 * 24 + h) * 144 + nn) * 32 + dd] = f2bf(v);
                    else             o2[((size_t)(w2 * 24 + h) * 32 + dd) * 144 + nn] = f2bf(v);
                }
            } else {
#pragma unroll
                for (int rg = 0; rg < 4; rg++) {
                    int R = Rbase + rg;
                    of[(size_t)R * Ndim + Cg] = acc[mf][nf][rg] + bv;
                }
            }
        }
    }
}

// ---------------- fused window attention: 1 block per (window, head), 9 waves ----------------
__global__ __launch_bounds__(576) void attn_kernel(const u16* __restrict__ Qg, const u16* __restrict__ Kg,
                                                   const u16* __restrict__ Vg, const float* __restrict__ bias_mat,
                                                   u16* __restrict__ Ob) {
    __shared__ __align__(16) u16 Qs[144 * 40];
    __shared__ __align__(16) u16 Ks[144 * 40];
    __shared__ __align__(16) u16 Vs[32 * 160];
    __shared__ __align__(16) u16 Ps[144 * 160];
    const int bx = blockIdx.x;
    const int w = bx / 24, h = bx - w * 24;
    const int wi = w & 3, wh = wi >> 1, ww = wi & 1;
    const int t = threadIdx.x, lane = t & 63, wv = t >> 6;
    const int l15 = lane & 15, lg = lane >> 4;
    const size_t base = (size_t)bx * 4608;
    {
        int nn = t >> 2, dd = (t & 3) << 3;
        *(u16x8*)(Qs + nn * 40 + dd) = *(const u16x8*)(Qg + base + nn * 32 + dd);
        *(u16x8*)(Ks + nn * 40 + dd) = *(const u16x8*)(Kg + base + nn * 32 + dd);
        int rv = t / 18, cv = (t - rv * 18) * 8;
        int ba = (rv * 320 + cv * 2) ^ ((rv & 7) << 4);
        *(u16x8*)((char*)Vs + ba) = *(const u16x8*)(Vg + base + rv * 144 + cv);
    }
    u16x8 zz = (u16x8)0;
    if (t < 64)  { int rv = t >> 1, cv = 144 + (t & 1) * 8; int ba = (rv * 320 + cv * 2) ^ ((rv & 7) << 4); *(u16x8*)((char*)Vs + ba) = zz; }
    if (t < 288) { int rv = t >> 1, cv = 144 + (t & 1) * 8; int ba = (rv * 320 + cv * 2) ^ ((rv & 7) << 4); *(u16x8*)((char*)Ps + ba) = zz; }
    __syncthreads();

    f32x4 S[9];
    {
        bf16x8 aq = *(const bf16x8*)(Qs + (wv * 16 + l15) * 40 + lg * 8);
        f32x4 z4 = (f32x4)0.0f;
#pragma unroll
        for (int j = 0; j < 9; j++) {
            bf16x8 bk = *(const bf16x8*)(Ks + (j * 16 + l15) * 40 + lg * 8);
            S[j] = __builtin_amdgcn_mfma_f32_16x16x32_bf16(aq, bk, z4, 0, 0, 0);
        }
    }
    int regm[9];
#pragma unroll
    for (int j = 0; j < 9; j++) {
        int m = j * 16 + l15; int r = m / 12, c = m - r * 12;
        int rid = wh ? (r < 6 ? 1 : 2) : 0;
        int cid = ww ? (c < 6 ? 1 : 2) : 0;
        regm[j] = rid * 3 + cid;
    }
    const float* bh = bias_mat + h * 20736;
#pragma unroll
    for (int rg = 0; rg < 4; rg++) {
        int n = wv * 16 + lg * 4 + rg;
        int r = n / 12, c = n - r * 12;
        int rid = wh ? (r < 6 ? 1 : 2) : 0;
        int cid = ww ? (c < 6 ? 1 : 2) : 0;
        int regn = rid * 3 + cid;
        const float* bhn = bh + n * 144;
        float mx = -1e30f;
#pragma unroll
        for (int j = 0; j < 9; j++) {
            float v = S[j][rg] + bhn[j * 16 + l15];
            if (regn != regm[j]) v -= 100.0f;
            S[j][rg] = v;
            mx = fmaxf(mx, v);
        }
#pragma unroll
        for (int d = 1; d < 16; d <<= 1) mx = fmaxf(mx, __shfl_xor(mx, d));
        float sum = 0.0f;
#pragma unroll
        for (int j = 0; j < 9; j++) { float e = __expf(S[j][rg] - mx); S[j][rg] = e; sum += e; }
#pragma unroll
        for (int d = 1; d < 16; d <<= 1) sum += __shfl_xor(sum, d);
        float inv = 1.0f / sum;
#pragma unroll
        for (int j = 0; j < 9; j++) {
            int ba = (n * 320 + (j * 16 + l15) * 2) ^ ((n & 7) << 4);
            *(u16*)((char*)Ps + ba) = f2bf(S[j][rg] * inv);
        }
    }
    __syncthreads();
    f32x4 o0 = (f32x4)0.0f, o1 = (f32x4)0.0f;
#pragma unroll
    for (int ks = 0; ks < 5; ks++) {
        int k2 = (ks * 32 + lg * 8) * 2;
        int ra = wv * 16 + l15;
        bf16x8 ap = *(const bf16x8*)((char*)Ps + ((ra * 320 + k2) ^ ((ra & 7) << 4)));
        int rv0 = l15, rv1 = 16 + l15;
        bf16x8 b0 = *(const bf16x8*)((char*)Vs + ((rv0 * 320 + k2) ^ ((rv0 & 7) << 4)));
        bf16x8 b1 = *(const bf16x8*)((char*)Vs + ((rv1 * 320 + k2) ^ ((rv1 & 7) << 4)));
        o0 = __builtin_amdgcn_mfma_f32_16x16x32_bf16(ap, b0, o0, 0, 0, 0);
        o1 = __builtin_amdgcn_mfma_f32_16x16x32_bf16(ap, b1, o1, 0, 0, 0);
    }
    // write Ob in 128-row PANEL layout for the proj GEMM: R = w*144+n, cols h*32 + d
#pragma unroll
    for (int rg = 0; rg < 4; rg++) {
        int n = wv * 16 + lg * 4 + rg;
        int R = w * 144 + n;
        size_t idx = ((size_t)(R >> 7) * 24 + h) * 4096 + (R & 127) * 32;
        Ob[idx + l15]      = f2bf(o0[rg]);
        Ob[idx + 16 + l15] = f2bf(o1[rg]);
    }
}

// ---------------- L2 norm + window-merge + reverse shift ----------------
__global__ __launch_bounds__(256) void norm_kernel(const float* __restrict__ raw, float* __restrict__ out) {
    int R = blockIdx.x * 4 + (threadIdx.x >> 6);
    int lane = threadIdx.x & 63;
    const float* src = raw + (size_t)R * 768;
    f32x4 v0 = *(const f32x4*)(src + lane * 4);
    f32x4 v1 = *(const f32x4*)(src + lane * 4 + 256);
    f32x4 v2 = *(const f32x4*)(src + lane * 4 + 512);
    float ss = v0[0]*v0[0] + v0[1]*v0[1] + v0[2]*v0[2] + v0[3]*v0[3]
             + v1[0]*v1[0] + v1[1]*v1[1] + v1[2]*v1[2] + v1[3]*v1[3]
             + v2[0]*v2[0] + v2[1]*v2[1] + v2[2]*v2[2] + v2[3]*v2[3];
#pragma unroll
    for (int d = 1; d < 64; d <<= 1) ss += __shfl_xor(ss, d);
    float inv = 1.0f / sqrtf(ss + 1e-6f);
    int w = R / 144, nn = R - w * 144;
    int b = w >> 2, wi = w & 3;
    int r = nn / 12, cc = nn - r * 12;
    int oh = (wi >> 1) * 12 + r + 6; if (oh >= 24) oh -= 24;
    int ow = (wi & 1) * 12 + cc + 6; if (ow >= 24) ow -= 24;
    float* dst = out + (((size_t)b * 24 + oh) * 24 + ow) * 768;
    v0 *= inv; v1 *= inv; v2 *= inv;
    *(f32x4*)(dst + lane * 4) = v0;
    *(f32x4*)(dst + lane * 4 + 256) = v1;
    *(f32x4*)(dst + lane * 4 + 512) = v2;
}

extern "C" void kernel_launch(void* const* d_in, const int* in_sizes, int n_in,
                              void* d_out, int out_size, void* d_ws, size_t ws_size,
                              hipStream_t stream) {
    const float* x      = (const float*)d_in[0];
    const float* qkv_w  = (const float*)d_in[1];
    const float* qkv_b  = (const float*)d_in[2];
    const float* proj_w = (const float*)d_in[3];
    const float* proj_b = (const float*)d_in[4];
    const float* rpb    = (const float*)d_in[5];
    const int*   rel    = (const int*)d_in[6];

    char* ws = (char*)d_ws;
    const size_t SZ = 56623104;  // 36864*768*2 bytes
    u16*   xw   = (u16*)(ws);
    u16*   Qb   = (u16*)(ws + SZ);
    u16*   Kb   = (u16*)(ws + 2 * SZ);
    u16*   Vt   = (u16*)(ws + 3 * SZ);
    u16*   Ob   = (u16*)(ws + 4 * SZ);
    u16*   qwt  = (u16*)(ws + 5 * SZ);
    u16*   pwt  = (u16*)(ws + 5 * SZ + 3538944);
    float* bm   = (float*)(ws + 5 * SZ + 3538944 + 1179648);
    float* raw  = (float*)(ws);  // aliases xw+Qb (dead by GEMM2)

    prep_x_kernel<<<27648, 256, 0, stream>>>(x, xw);
    transpose_cast_kernel<<<dim3(72, 24), 256, 0, stream>>>(qkv_w, qwt, 768, 2304);
    transpose_cast_kernel<<<dim3(24, 24), 256, 0, stream>>>(proj_w, pwt, 768, 768);
    make_bias_kernel<<<1944, 256, 0, stream>>>(rpb, rel, bm);

    gemm128_kernel<0><<<5184, 256, 0, stream>>>(xw, qwt, qkv_b, Qb, Kb, Vt, nullptr,
                                                2304, 768, 18, 0.17677669529663687f);
    attn_kernel<<<6144, 576, 0, stream>>>(Qb, Kb, Vt, bm, Ob);
    gemm128_kernel<1><<<1728, 256, 0, stream>>>(Ob, pwt, proj_b, nullptr, nullptr, nullptr,
                                                raw, 768, 768, 6, 1.0f);
    norm_kernel<<<9216, 256, 0, stream>>>(raw, (float*)d_out);
}